// Round 1
// baseline (3224.969 us; speedup 1.0000x reference)
//
#include <hip/hip_runtime.h>

#define QN 8192   // trajectories
#define MN 2048   // time steps
#define HN 64     // hidden units
#define LPT 16    // lanes per trajectory
#define UPL 4     // hidden units per lane (HN / LPT)

// ds_swizzle XOR-mode butterfly exchange within 32-lane halves.
// imm = (xor_mask<<10) | (or_mask<<5) | and_mask ; and=0x1F, or=0.
template <int IMM>
__device__ __forceinline__ float swz(float v) {
    return __int_as_float(__builtin_amdgcn_ds_swizzle(__float_as_int(v), IMM));
}

__global__ __launch_bounds__(256, 2) void rk4_nss_kernel(
    const float* __restrict__ x0p,   // (Q,2)
    const float* __restrict__ up,    // (M,Q)
    const float* __restrict__ W1,    // (3,H)
    const float* __restrict__ b1,    // (H)
    const float* __restrict__ W2,    // (H,2)
    const float* __restrict__ b2,    // (2)
    float* __restrict__ out)         // (M,Q,2)
{
    const int tid  = blockIdx.x * 256 + threadIdx.x;
    const int lane = threadIdx.x & (LPT - 1);
    const int traj = tid >> 4;              // tid / LPT
    if (traj >= QN) return;

    // Per-lane weights: this lane owns hidden units j = lane + k*LPT.
    float w10[UPL], w11[UPL], w12[UPL], bb[UPL], w20[UPL], w21[UPL];
#pragma unroll
    for (int k = 0; k < UPL; ++k) {
        const int j = lane + k * LPT;
        w10[k] = W1[j];
        w11[k] = W1[HN + j];
        w12[k] = W1[2 * HN + j];
        bb[k]  = b1[j];
        w20[k] = W2[2 * j];
        w21[k] = W2[2 * j + 1];
    }
    const float b20 = b2[0], b21 = b2[1];

    float xa = x0p[2 * traj];
    float xb = x0p[2 * traj + 1];
    float ucur = up[traj];

    float2* outv = reinterpret_cast<float2*>(out);

    // f(x,u): each lane computes 4 hidden units, partial dx accumulated
    // in-lane, then 4-stage xor butterfly over the 16-lane group.
    auto feval = [&](float ia, float ib, float uu, float& d0, float& d1) {
        float p0 = 0.0f, p1 = 0.0f;
#pragma unroll
        for (int k = 0; k < UPL; ++k) {
            float pre = fmaf(w10[k], ia,
                        fmaf(w11[k], ib,
                        fmaf(w12[k], uu, bb[k])));
            pre = fminf(fmaxf(pre, -15.0f), 15.0f);
            // tanh(x) = (e-1)/(e+1), e = 2^(x * 2*log2(e))
            float e   = __builtin_amdgcn_exp2f(pre * 2.8853900817779268f);
            float num = e - 1.0f;
            float den = e + 1.0f;
            float r   = __builtin_amdgcn_rcpf(den);
            r = r * fmaf(-den, r, 2.0f);           // Newton: ~1 ulp
            float th = num * r;
            p0 = fmaf(th, w20[k], p0);
            p1 = fmaf(th, w21[k], p1);
        }
        p0 += swz<0x041F>(p0);  p1 += swz<0x041F>(p1);   // xor 1
        p0 += swz<0x081F>(p0);  p1 += swz<0x081F>(p1);   // xor 2
        p0 += swz<0x101F>(p0);  p1 += swz<0x101F>(p1);   // xor 4
        p0 += swz<0x201F>(p0);  p1 += swz<0x201F>(p1);   // xor 8
        d0 = p0 + b20;
        d1 = p1 + b21;
    };

    for (int t = 0; t < MN; ++t) {
        // Output is the state BEFORE the update.
        if (lane == 0) {
            outv[t * QN + traj] = make_float2(xa, xb);
        }
        // Prefetch next step's input (hides HBM/L2 latency under VALU work).
        const float unext = (t + 1 < MN) ? up[(t + 1) * QN + traj] : 0.0f;

        float k1a, k1b, k2a, k2b, k3a, k3b, k4a, k4b;
        feval(xa, xb, ucur, k1a, k1b);
        feval(fmaf(0.5f, k1a, xa), fmaf(0.5f, k1b, xb), ucur, k2a, k2b);
        feval(fmaf(0.5f, k2a, xa), fmaf(0.5f, k2b, xb), ucur, k3a, k3b);
        feval(xa + k3a, xb + k3b, ucur, k4a, k4b);

        xa += (1.0f / 6.0f) * (k1a + 2.0f * (k2a + k3a) + k4a);
        xb += (1.0f / 6.0f) * (k1b + 2.0f * (k2b + k3b) + k4b);
        ucur = unext;
    }
}

extern "C" void kernel_launch(void* const* d_in, const int* in_sizes, int n_in,
                              void* d_out, int out_size, void* d_ws, size_t ws_size,
                              hipStream_t stream) {
    const float* x0 = (const float*)d_in[0];
    const float* u  = (const float*)d_in[1];
    const float* W1 = (const float*)d_in[2];
    const float* b1 = (const float*)d_in[3];
    const float* W2 = (const float*)d_in[4];
    const float* b2 = (const float*)d_in[5];
    float* out = (float*)d_out;

    // 8192 trajectories * 16 lanes = 131072 threads = 512 blocks of 256.
    const int threads = 256;
    const int blocks  = (QN * LPT) / threads;
    rk4_nss_kernel<<<blocks, threads, 0, stream>>>(x0, u, W1, b1, W2, b2, out);
}

// Round 2
// 2306.418 us; speedup vs baseline: 1.3983x; 1.3983x over previous
//
#include <hip/hip_runtime.h>

#define QN 8192   // trajectories
#define MN 2048   // time steps
#define HN 64     // hidden units
#define LPT 16    // lanes per trajectory
#define UPL 4     // hidden units per lane (HN / LPT)

// DPP-based butterfly add within each 16-lane group (one DPP "row").
// Stages: xor1 (quad_perm [1,0,3,2]), xor2 (quad_perm [2,3,0,1]),
// cross-quad (row_half_mirror), cross-half (row_mirror).
// After stages 1-2 the quad sum is uniform in each quad, so the mirror
// controls (which reverse rather than xor) still fetch the complementary
// group's value. All full-rate VALU, no LDS.
template <int CTRL>
__device__ __forceinline__ float dpp_add(float v) {
    int m = __builtin_amdgcn_update_dpp(0, __float_as_int(v), CTRL, 0xf, 0xf, true);
    return v + __int_as_float(m);
}
#define DPP_QUAD_XOR1 0xB1   // quad_perm [1,0,3,2]
#define DPP_QUAD_XOR2 0x4E   // quad_perm [2,3,0,1]
#define DPP_HALF_MIRR 0x141  // row_half_mirror
#define DPP_ROW_MIRR  0x140  // row_mirror

__global__ __launch_bounds__(256, 2) void rk4_nss_kernel(
    const float* __restrict__ x0p,   // (Q,2)
    const float* __restrict__ up,    // (M,Q)
    const float* __restrict__ W1,    // (3,H)
    const float* __restrict__ b1,    // (H)
    const float* __restrict__ W2,    // (H,2)
    const float* __restrict__ b2,    // (2)
    float* __restrict__ out)         // (M,Q,2)
{
    const int tid  = blockIdx.x * 256 + threadIdx.x;
    const int lane = threadIdx.x & (LPT - 1);
    const int traj = tid >> 4;
    if (traj >= QN) return;

    // Per-lane weights: this lane owns hidden units j = lane + k*LPT.
    float w10[UPL], w11[UPL], w12[UPL], bb[UPL], w20[UPL], w21[UPL];
#pragma unroll
    for (int k = 0; k < UPL; ++k) {
        const int j = lane + k * LPT;
        w10[k] = W1[j];
        w11[k] = W1[HN + j];
        w12[k] = W1[2 * HN + j];
        bb[k]  = b1[j];
        w20[k] = W2[2 * j];
        w21[k] = W2[2 * j + 1];
    }
    const float b20 = b2[0], b21 = b2[1];

    float xa = x0p[2 * traj];
    float xb = x0p[2 * traj + 1];
    float ucur = up[traj];

    float2* outv = reinterpret_cast<float2*>(out);

    // u-dependent part of the preactivation, constant across the 4 fevals.
    float pb[UPL];

    auto feval = [&](float ia, float ib, float& d0, float& d1) {
        float p0 = 0.0f, p1 = 0.0f;
#pragma unroll
        for (int k = 0; k < UPL; ++k) {
            float pre = fmaf(w10[k], ia, fmaf(w11[k], ib, pb[k]));
            pre = __builtin_amdgcn_fmed3f(pre, -15.0f, 15.0f);
            // tanh(x) = 1 - 2/(e^{2x}+1); e^{2x} = 2^(x * 2*log2 e)
            float e  = __builtin_amdgcn_exp2f(pre * 2.8853900817779268f);
            float r  = __builtin_amdgcn_rcpf(e + 1.0f);   // ~1 ulp on gfx9+
            float th = fmaf(-2.0f, r, 1.0f);
            p0 = fmaf(th, w20[k], p0);
            p1 = fmaf(th, w21[k], p1);
        }
        p0 = dpp_add<DPP_QUAD_XOR1>(p0);  p1 = dpp_add<DPP_QUAD_XOR1>(p1);
        p0 = dpp_add<DPP_QUAD_XOR2>(p0);  p1 = dpp_add<DPP_QUAD_XOR2>(p1);
        p0 = dpp_add<DPP_HALF_MIRR>(p0);  p1 = dpp_add<DPP_HALF_MIRR>(p1);
        p0 = dpp_add<DPP_ROW_MIRR>(p0);   p1 = dpp_add<DPP_ROW_MIRR>(p1);
        d0 = p0 + b20;
        d1 = p1 + b21;
    };

    for (int t = 0; t < MN; ++t) {
        // Output is the state BEFORE the update.
        if (lane == 0) {
            outv[t * QN + traj] = make_float2(xa, xb);
        }
        // Prefetch next step's input (hides HBM/L2 latency under VALU work).
        const float unext = (t + 1 < MN) ? up[(t + 1) * QN + traj] : 0.0f;

#pragma unroll
        for (int k = 0; k < UPL; ++k)
            pb[k] = fmaf(w12[k], ucur, bb[k]);

        float k1a, k1b, k2a, k2b, k3a, k3b, k4a, k4b;
        feval(xa, xb, k1a, k1b);
        feval(fmaf(0.5f, k1a, xa), fmaf(0.5f, k1b, xb), k2a, k2b);
        feval(fmaf(0.5f, k2a, xa), fmaf(0.5f, k2b, xb), k3a, k3b);
        feval(xa + k3a, xb + k3b, k4a, k4b);

        xa += (1.0f / 6.0f) * (k1a + 2.0f * (k2a + k3a) + k4a);
        xb += (1.0f / 6.0f) * (k1b + 2.0f * (k2b + k3b) + k4b);
        ucur = unext;
    }
}

extern "C" void kernel_launch(void* const* d_in, const int* in_sizes, int n_in,
                              void* d_out, int out_size, void* d_ws, size_t ws_size,
                              hipStream_t stream) {
    const float* x0 = (const float*)d_in[0];
    const float* u  = (const float*)d_in[1];
    const float* W1 = (const float*)d_in[2];
    const float* b1 = (const float*)d_in[3];
    const float* W2 = (const float*)d_in[4];
    const float* b2 = (const float*)d_in[5];
    float* out = (float*)d_out;

    const int threads = 256;
    const int blocks  = (QN * LPT) / threads;
    rk4_nss_kernel<<<blocks, threads, 0, stream>>>(x0, u, W1, b1, W2, b2, out);
}

// Round 3
// 1891.533 us; speedup vs baseline: 1.7049x; 1.2193x over previous
//
#include <hip/hip_runtime.h>

#define QN 8192   // trajectories
#define MN 2048   // time steps
#define HN 64     // hidden units
#define LPT 16    // lanes per trajectory
#define UPL 4     // hidden units per lane (HN / LPT)

// DPP-based butterfly add within each 16-lane group (one DPP "row").
// All full-rate VALU, no LDS. Identical to the R2 version that passed.
template <int CTRL>
__device__ __forceinline__ float dpp_add(float v) {
    int m = __builtin_amdgcn_update_dpp(0, __float_as_int(v), CTRL, 0xf, 0xf, true);
    return v + __int_as_float(m);
}
#define DPP_QUAD_XOR1 0xB1   // quad_perm [1,0,3,2]
#define DPP_QUAD_XOR2 0x4E   // quad_perm [2,3,0,1]
#define DPP_HALF_MIRR 0x141  // row_half_mirror
#define DPP_ROW_MIRR  0x140  // row_mirror

__global__ __launch_bounds__(256, 2) void rk4_nss_kernel(
    const float* __restrict__ x0p,   // (Q,2)
    const float* __restrict__ up,    // (M,Q)
    const float* __restrict__ W1,    // (3,H)
    const float* __restrict__ b1,    // (H)
    const float* __restrict__ W2,    // (H,2)
    const float* __restrict__ b2,    // (2)
    float* __restrict__ out)         // (M,Q,2)
{
    const int tid  = blockIdx.x * 256 + threadIdx.x;
    const int lane = threadIdx.x & (LPT - 1);
    const int traj = tid >> 4;
    if (traj >= QN) return;

    const float SC = 2.8853900817779268f;  // 2*log2(e): e^{2x} = 2^(SC*x)

    // Per-lane weights, pre-scaled so the exp argument needs no extra mul.
    // tanh(x) = 1 - 2/(e^{2x}+1); fold the "+1*w2" into constants c0,c1 and
    // accumulate inv_k * (-2*w2_k) directly.
    float ws10[UPL], ws11[UPL], ws12[UPL], bsb[UPL], w20n[UPL], w21n[UPL];
#pragma unroll
    for (int k = 0; k < UPL; ++k) {
        const int j = lane + k * LPT;
        ws10[k] = W1[j] * SC;
        ws11[k] = W1[HN + j] * SC;
        ws12[k] = W1[2 * HN + j] * SC;
        bsb[k]  = b1[j] * SC;
        w20n[k] = -2.0f * W2[2 * j];
        w21n[k] = -2.0f * W2[2 * j + 1];
    }
    float c0 = b2[0], c1 = b2[1];
    for (int j = 0; j < HN; ++j) {   // init-time only; W2 is 512 B, L1-hot
        c0 += W2[2 * j];
        c1 += W2[2 * j + 1];
    }

    float xa = x0p[2 * traj];
    float xb = x0p[2 * traj + 1];
    float ucur = up[traj];

    float2* outv = reinterpret_cast<float2*>(out);

    float pb[UPL];  // u-dependent preactivation part, constant across 4 fevals

    auto feval = [&](float ia, float ib, float& d0, float& d1) {
        float dden[UPL];
#pragma unroll
        for (int k = 0; k < UPL; ++k) {
            float pre = fmaf(ws10[k], ia, fmaf(ws11[k], ib, pb[k]));
            pre = __builtin_amdgcn_fmed3f(pre, -43.0f, 43.0f);
            dden[k] = __builtin_amdgcn_exp2f(pre) + 1.0f;
        }
        // Pair-batched reciprocal: 2 rcp instead of 4 (trans ops are 1/8 rate).
        // Product <= (e^30+1)^2 ~ 1.1e26, no overflow; ~2 ulp error.
        float r01 = __builtin_amdgcn_rcpf(dden[0] * dden[1]);
        float r23 = __builtin_amdgcn_rcpf(dden[2] * dden[3]);
        float inv0 = r01 * dden[1];
        float inv1 = r01 * dden[0];
        float inv2 = r23 * dden[3];
        float inv3 = r23 * dden[2];

        float p0 = fmaf(inv0, w20n[0],
                   fmaf(inv1, w20n[1],
                   fmaf(inv2, w20n[2], inv3 * w20n[3])));
        float p1 = fmaf(inv0, w21n[0],
                   fmaf(inv1, w21n[1],
                   fmaf(inv2, w21n[2], inv3 * w21n[3])));

        p0 = dpp_add<DPP_QUAD_XOR1>(p0);  p1 = dpp_add<DPP_QUAD_XOR1>(p1);
        p0 = dpp_add<DPP_QUAD_XOR2>(p0);  p1 = dpp_add<DPP_QUAD_XOR2>(p1);
        p0 = dpp_add<DPP_HALF_MIRR>(p0);  p1 = dpp_add<DPP_HALF_MIRR>(p1);
        p0 = dpp_add<DPP_ROW_MIRR>(p0);   p1 = dpp_add<DPP_ROW_MIRR>(p1);
        d0 = p0 + c0;
        d1 = p1 + c1;
    };

    for (int t = 0; t < MN; ++t) {
        // Output is the state BEFORE the update.
        if (lane == 0) {
            outv[t * QN + traj] = make_float2(xa, xb);
        }
        // Prefetch next step's input (hides HBM/L2 latency under VALU work).
        const float unext = (t + 1 < MN) ? up[(t + 1) * QN + traj] : 0.0f;

#pragma unroll
        for (int k = 0; k < UPL; ++k)
            pb[k] = fmaf(ws12[k], ucur, bsb[k]);

        float k1a, k1b, k2a, k2b, k3a, k3b, k4a, k4b;
        feval(xa, xb, k1a, k1b);
        feval(fmaf(0.5f, k1a, xa), fmaf(0.5f, k1b, xb), k2a, k2b);
        feval(fmaf(0.5f, k2a, xa), fmaf(0.5f, k2b, xb), k3a, k3b);
        feval(xa + k3a, xb + k3b, k4a, k4b);

        float ta = k2a + k3a;
        float sa = k1a + k4a;
        xa = fmaf((1.0f / 6.0f), fmaf(2.0f, ta, sa), xa);
        float tb = k2b + k3b;
        float sb = k1b + k4b;
        xb = fmaf((1.0f / 6.0f), fmaf(2.0f, tb, sb), xb);
        ucur = unext;
    }
}

extern "C" void kernel_launch(void* const* d_in, const int* in_sizes, int n_in,
                              void* d_out, int out_size, void* d_ws, size_t ws_size,
                              hipStream_t stream) {
    const float* x0 = (const float*)d_in[0];
    const float* u  = (const float*)d_in[1];
    const float* W1 = (const float*)d_in[2];
    const float* b1 = (const float*)d_in[3];
    const float* W2 = (const float*)d_in[4];
    const float* b2 = (const float*)d_in[5];
    float* out = (float*)d_out;

    const int threads = 256;
    const int blocks  = (QN * LPT) / threads;
    rk4_nss_kernel<<<blocks, threads, 0, stream>>>(x0, u, W1, b1, W2, b2, out);
}